// Round 4
// baseline (582.852 us; speedup 1.0000x reference)
//
#include <hip/hip_runtime.h>
#include <hip/hip_bf16.h>
#include <cstddef>
#include <cfloat>

#define HD 256   // hidden dim
#define KD 512   // concat K (mean | self)
#define NH 28    // total head outputs (21+2+5)

typedef __attribute__((ext_vector_type(8))) short bf16x8;
typedef __attribute__((ext_vector_type(4))) float f32x4;

__device__ inline float bf2f(unsigned short u) { return __uint_as_float(((unsigned)u) << 16); }
__device__ inline unsigned short f2bf(float f) {
    __hip_bfloat16 h = __float2bfloat16(f);
    return *(unsigned short*)&h;
}

// ---------------- CSR build ----------------
__global__ void hist_kernel(const int* __restrict__ dst, int* __restrict__ cnt, int E) {
    int e = blockIdx.x * blockDim.x + threadIdx.x;
    if (e < E) atomicAdd(&cnt[dst[e]], 1);
}

__global__ void chunk_reduce_kernel(const int* __restrict__ cnt, int* __restrict__ bsum, int n) {
    __shared__ int sdata[4];
    int idx = blockIdx.x * 256 + threadIdx.x;
    int v = (idx < n) ? cnt[idx] : 0;
    for (int off = 32; off > 0; off >>= 1) v += __shfl_down(v, off, 64);
    int lane = threadIdx.x & 63, wv = threadIdx.x >> 6;
    if (lane == 0) sdata[wv] = v;
    __syncthreads();
    if (threadIdx.x == 0) bsum[blockIdx.x] = sdata[0] + sdata[1] + sdata[2] + sdata[3];
}

__global__ void scan_chunks_kernel(const int* __restrict__ bsum, int* __restrict__ boff,
                                   int nchunks, int* __restrict__ row_ptr_end, int E) {
    int t = threadIdx.x;
    int v = (t < nchunks) ? bsum[t] : 0;
    int lane = t & 63, wv = t >> 6;
    int incl = v;
    for (int off = 1; off < 64; off <<= 1) { int u = __shfl_up(incl, off, 64); if (lane >= off) incl += u; }
    __shared__ int wsum[4];
    if (lane == 63) wsum[wv] = incl;
    __syncthreads();
    int base = 0;
    for (int w2 = 0; w2 < 4; ++w2) if (w2 < wv) base += wsum[w2];
    if (t < nchunks) boff[t] = base + incl - v;
    if (t == 0) *row_ptr_end = E;
}

__global__ void scan_final_kernel(const int* __restrict__ cnt, const int* __restrict__ boff,
                                  int* __restrict__ row_ptr, float* __restrict__ invdeg, int n) {
    int idx = blockIdx.x * 256 + threadIdx.x;
    int v = (idx < n) ? cnt[idx] : 0;
    int lane = threadIdx.x & 63, wv = threadIdx.x >> 6;
    int incl = v;
    for (int off = 1; off < 64; off <<= 1) { int u = __shfl_up(incl, off, 64); if (lane >= off) incl += u; }
    __shared__ int wsum[4];
    if (lane == 63) wsum[wv] = incl;
    __syncthreads();
    int base = 0;
    for (int w2 = 0; w2 < 4; ++w2) if (w2 < wv) base += wsum[w2];
    if (idx < n) {
        row_ptr[idx] = boff[blockIdx.x] + base + incl - v;
        invdeg[idx] = 1.0f / fmaxf((float)v, 1.0f);
    }
}

__global__ void scatter_kernel(const int* __restrict__ src, const int* __restrict__ dst,
                               const int* __restrict__ row_ptr, int* __restrict__ cursor,
                               int* __restrict__ col_idx, int E) {
    int e = blockIdx.x * blockDim.x + threadIdx.x;
    if (e < E) {
        int d = dst[e];
        int pos = atomicAdd(&cursor[d], 1);
        col_idx[row_ptr[d] + pos] = src[e];
    }
}

// ---------------- weight packing ----------------
__global__ void pack_layer_w(const float* __restrict__ wl, const float* __restrict__ wr,
                             unsigned short* __restrict__ dst) {
    int idx = blockIdx.x * 256 + threadIdx.x;   // 256*512 total
    if (idx >= HD * KD) return;
    int nn = idx >> 9, k = idx & 511;
    float v = (k < HD) ? wl[nn * HD + k] : wr[nn * HD + (k - HD)];
    dst[idx] = f2bf(v);
}

// W2[64][256]: rows 0..27 = L heads, rows 32..59 = R heads, rest zero
__global__ void pack_heads2(const float* __restrict__ wal, const float* __restrict__ war,
                            const float* __restrict__ wsl, const float* __restrict__ wsr,
                            const float* __restrict__ wel, const float* __restrict__ wer,
                            const float* __restrict__ ba, const float* __restrict__ bs,
                            const float* __restrict__ be,
                            unsigned short* __restrict__ W2, float* __restrict__ bcat) {
    int idx = blockIdx.x * 256 + threadIdx.x;   // 64*256 total
    if (idx >= 64 * HD) return;
    int o = idx >> 8, k = idx & 255;
    float v = 0.f;
    if (o < 21)                    v = wal[o * HD + k];
    else if (o < 23)               v = wsl[(o - 21) * HD + k];
    else if (o < 28)               v = wel[(o - 23) * HD + k];
    else if (o >= 32 && o < 53)    v = war[(o - 32) * HD + k];
    else if (o >= 53 && o < 55)    v = wsr[(o - 53) * HD + k];
    else if (o >= 55 && o < 60)    v = wer[(o - 55) * HD + k];
    W2[idx] = f2bf(v);
    if (k == 0 && o < 32) {
        float b = 0.f;
        if (o < 21) b = ba[o]; else if (o < 23) b = bs[o - 21]; else if (o < 28) b = be[o - 23];
        bcat[o] = b;
    }
}

// x fp32 -> bf16 into right half of [N][512] buffer
__global__ void convert_x_kernel(const float* __restrict__ x, unsigned short* __restrict__ buf, int n) {
    int idx = blockIdx.x * 256 + threadIdx.x;   // n*64
    if (idx >= n * 64) return;
    int r = idx >> 6, c4 = (idx & 63) * 4;
    float4 v = ((const float4*)x)[idx];
    ushort4 o;
    o.x = f2bf(v.x); o.y = f2bf(v.y); o.z = f2bf(v.z); o.w = f2bf(v.w);
    *(ushort4*)&buf[(size_t)r * KD + HD + c4] = o;
}

// ---------------- mean aggregation with BN+ReLU on read ----------------
// buf right half holds RAW Z_{l-1}; this kernel applies h = max(sc*z+sh, lo) per gathered
// element (sc/sh from prev layer stats; identity for layer 1), writes mean(h) to left half.
// One node per 64-lane wave; lane parity (lane>>5) picks neighbor within a pair; 16B/lane.
// Block 0 also zeroes THIS layer's stat buffers (filled later by gemm's atomics).
__global__ __launch_bounds__(256) void agg_mean_fused(
        unsigned short* __restrict__ buf,
        const int* __restrict__ row_ptr, const int* __restrict__ col_idx,
        const float* __restrict__ invdeg,
        const float* __restrict__ psum, const float* __restrict__ psumsq,
        const float* __restrict__ g, const float* __restrict__ bt,
        float* __restrict__ zsum, float* __restrict__ zsumsq,
        int apply, int n) {
    __shared__ float sc_s[HD], sh_s[HD];
    int t = threadIdx.x;
    if (blockIdx.x == 0) { zsum[t] = 0.f; zsumsq[t] = 0.f; }
    if (apply) {
        float fn = (float)n;
        float mu = psum[t] / fn;
        float var = psumsq[t] / fn - mu * mu;
        float s = g[t] / sqrtf(var + 1e-5f);
        sc_s[t] = s; sh_s[t] = bt[t] - mu * s;
    } else { sc_s[t] = 1.f; sh_s[t] = 0.f; }
    __syncthreads();

    int wv = t >> 6, lane = t & 63;
    int node = blockIdx.x * 4 + wv;
    if (node >= n) return;
    int par = lane >> 5;      // neighbor parity within a pair
    int c16 = lane & 31;      // 16B chunk (8 bf16 cols) within the row
    float lo = apply ? 0.f : -FLT_MAX;
    float sc_r[8], sh_r[8];
#pragma unroll
    for (int k = 0; k < 8; ++k) { sc_r[k] = sc_s[c16 * 8 + k]; sh_r[k] = sh_s[c16 * 8 + k]; }
    const unsigned short* src = buf + HD + c16 * 8;
    int s = row_ptr[node], e = row_ptr[node + 1];
    float a[8];
#pragma unroll
    for (int k = 0; k < 8; ++k) a[k] = 0.f;
    int i = s;
    for (; i + 8 <= e; i += 8) {
        int j0 = col_idx[i + par];
        int j1 = col_idx[i + 2 + par];
        int j2 = col_idx[i + 4 + par];
        int j3 = col_idx[i + 6 + par];
        float4 v0 = *(const float4*)(src + (size_t)j0 * KD);
        float4 v1 = *(const float4*)(src + (size_t)j1 * KD);
        float4 v2 = *(const float4*)(src + (size_t)j2 * KD);
        float4 v3 = *(const float4*)(src + (size_t)j3 * KD);
        const unsigned short* u0 = (const unsigned short*)&v0;
        const unsigned short* u1 = (const unsigned short*)&v1;
        const unsigned short* u2 = (const unsigned short*)&v2;
        const unsigned short* u3 = (const unsigned short*)&v3;
#pragma unroll
        for (int k = 0; k < 8; ++k) {
            a[k] += fmaxf(bf2f(u0[k]) * sc_r[k] + sh_r[k], lo);
            a[k] += fmaxf(bf2f(u1[k]) * sc_r[k] + sh_r[k], lo);
            a[k] += fmaxf(bf2f(u2[k]) * sc_r[k] + sh_r[k], lo);
            a[k] += fmaxf(bf2f(u3[k]) * sc_r[k] + sh_r[k], lo);
        }
    }
    for (; i + 2 <= e; i += 2) {
        int j = col_idx[i + par];
        float4 v = *(const float4*)(src + (size_t)j * KD);
        const unsigned short* u = (const unsigned short*)&v;
#pragma unroll
        for (int k = 0; k < 8; ++k) a[k] += fmaxf(bf2f(u[k]) * sc_r[k] + sh_r[k], lo);
    }
    if (i < e) {   // odd tail: only parity-0 lanes contribute
        int j = col_idx[i];
        float4 v = *(const float4*)(src + (size_t)j * KD);
        const unsigned short* u = (const unsigned short*)&v;
        if (par == 0) {
#pragma unroll
            for (int k = 0; k < 8; ++k) a[k] += fmaxf(bf2f(u[k]) * sc_r[k] + sh_r[k], lo);
        }
    }
#pragma unroll
    for (int k = 0; k < 8; ++k) a[k] += __shfl_xor(a[k], 32, 64);
    float inv = invdeg[node];
    unsigned short ob[8];
#pragma unroll
    for (int k = 0; k < 8; ++k) ob[k] = f2bf(a[k] * inv);
    if (par == 0) *(float4*)&buf[(size_t)node * KD + c16 * 8] = *(const float4*)ob;
}

// ---------------- MFMA GEMM + fused BN-on-read (A right half) + fused BN stats ----------------
// Z[n,256] = [mean | BN(rawZ)] @ W[256,512]^T; writes raw Z bf16 into nxt right half;
// atomically accumulates per-column sum/sumsq. 512 threads, 128x256 tile, BK=64.
#define SWIZ(row, kc) (((row) << 6) + ((((kc) ^ ((row) & 7))) << 3))

__global__ __launch_bounds__(512) void gemm_mfma_stats(
        const unsigned short* __restrict__ A, const unsigned short* __restrict__ W,
        unsigned short* __restrict__ Zb,
        const float* __restrict__ psum, const float* __restrict__ psumsq,
        const float* __restrict__ g, const float* __restrict__ bt,
        float* __restrict__ colsum, float* __restrict__ colsumsq,
        int apply, int n) {
    __shared__ __align__(16) short As[128 * 64];
    __shared__ __align__(16) short Bs[256 * 64];
    __shared__ float sc_s[HD], sh_s[HD];
    int t = threadIdx.x;
    if (t < HD) {
        if (apply) {
            float fn = (float)n;
            float mu = psum[t] / fn;
            float var = psumsq[t] / fn - mu * mu;
            float s = g[t] / sqrtf(var + 1e-5f);
            sc_s[t] = s; sh_s[t] = bt[t] - mu * s;
        } else { sc_s[t] = 1.f; sh_s[t] = 0.f; }
    }
    __syncthreads();
    float lo = apply ? 0.f : -FLT_MAX;

    int wave = t >> 6, lane = t & 63;
    int wm = wave & 1, wn = wave >> 1;          // wm: row half, wn: col quarter
    int lm = lane & 15, q = lane >> 4;
    int r0 = blockIdx.x * 128;

    f32x4 acc[4][4];
#pragma unroll
    for (int i = 0; i < 4; ++i)
#pragma unroll
        for (int j = 0; j < 4; ++j) acc[i][j] = (f32x4){0.f, 0.f, 0.f, 0.f};

    int srow = t >> 3;     // 0..63
    int skc = t & 7;

    for (int kt = 0; kt < 8; ++kt) {
        int kc = kt * 64;
        bool rh = (kt >= 4);                 // right half (self features, raw Z) -> transform
        float scr[8], shr[8];
        if (rh) {
            int cb = kc - HD + skc * 8;
            *(float4*)&scr[0] = *(const float4*)&sc_s[cb];
            *(float4*)&scr[4] = *(const float4*)&sc_s[cb + 4];
            *(float4*)&shr[0] = *(const float4*)&sh_s[cb];
            *(float4*)&shr[4] = *(const float4*)&sh_s[cb + 4];
        }
#pragma unroll
        for (int u = 0; u < 2; ++u) {           // A: 128 rows
            int row = srow + u * 64;
            int ga = r0 + row; if (ga >= n) ga = n - 1;
            float4 av = *(const float4*)&A[(size_t)ga * KD + kc + skc * 8];
            if (rh) {
                unsigned short* us = (unsigned short*)&av;
#pragma unroll
                for (int k2 = 0; k2 < 8; ++k2)
                    us[k2] = f2bf(fmaxf(bf2f(us[k2]) * scr[k2] + shr[k2], lo));
            }
            *(float4*)&As[SWIZ(row, skc)] = av;
        }
#pragma unroll
        for (int u = 0; u < 4; ++u) {           // W: 256 rows
            int row = srow + u * 64;
            *(float4*)&Bs[SWIZ(row, skc)] = *(const float4*)&W[(size_t)row * KD + kc + skc * 8];
        }
        __syncthreads();
#pragma unroll
        for (int kk = 0; kk < 2; ++kk) {
            bf16x8 af[4], bfv[4];
#pragma unroll
            for (int i = 0; i < 4; ++i)
                af[i] = *(bf16x8*)&As[SWIZ(wm * 64 + i * 16 + lm, kk * 4 + q)];
#pragma unroll
            for (int j = 0; j < 4; ++j)
                bfv[j] = *(bf16x8*)&Bs[SWIZ(wn * 64 + j * 16 + lm, kk * 4 + q)];
#pragma unroll
            for (int i = 0; i < 4; ++i)
#pragma unroll
                for (int j = 0; j < 4; ++j)
                    acc[i][j] = __builtin_amdgcn_mfma_f32_16x16x32_bf16(af[i], bfv[j], acc[i][j], 0, 0, 0);
        }
        __syncthreads();
    }

    // epilogue: write raw Z bf16 + per-column stats
    // C/D layout: col = lane&15, row = q*4 + reg  [m89/m91 verified]
    float s[4], s2[4];
#pragma unroll
    for (int j = 0; j < 4; ++j) { s[j] = 0.f; s2[j] = 0.f; }
#pragma unroll
    for (int i = 0; i < 4; ++i) {
        int rbase = r0 + wm * 64 + i * 16 + q * 4;
#pragma unroll
        for (int reg = 0; reg < 4; ++reg) {
            int r = rbase + reg;
            if (r < n) {
#pragma unroll
                for (int j = 0; j < 4; ++j) {
                    float v = acc[i][j][reg];
                    int c = wn * 64 + j * 16 + lm;
                    Zb[(size_t)r * KD + HD + c] = f2bf(v);
                    s[j] += v; s2[j] += v * v;
                }
            }
        }
    }
#pragma unroll
    for (int j = 0; j < 4; ++j) {
        s[j]  += __shfl_xor(s[j], 16, 64);  s[j]  += __shfl_xor(s[j], 32, 64);
        s2[j] += __shfl_xor(s2[j], 16, 64); s2[j] += __shfl_xor(s2[j], 32, 64);
    }
    if (lane < 16) {
#pragma unroll
        for (int j = 0; j < 4; ++j) {
            int c = wn * 64 + j * 16 + lm;
            atomicAdd(&colsum[c], s[j]);
            atomicAdd(&colsumsq[c], s2[j]);
        }
    }
}

// ---------------- heads: P = BN3(h3raw) @ W2^T  (PL = L-heads, PR = R-heads) ----------------
// A = cur right half (raw Z3, stride KD), K=256, BN applied on staging. PL/PR [N][32] bf16.
__global__ __launch_bounds__(256) void heads_pgemm(const unsigned short* __restrict__ A,
                                                   const unsigned short* __restrict__ W2,
                                                   const float* __restrict__ psum,
                                                   const float* __restrict__ psumsq,
                                                   const float* __restrict__ g,
                                                   const float* __restrict__ bt,
                                                   unsigned short* __restrict__ PL,
                                                   unsigned short* __restrict__ PR, int n) {
    __shared__ __align__(16) short As[128 * 64];
    __shared__ __align__(16) short Bs[64 * 64];
    __shared__ float sc_s[HD], sh_s[HD];
    int t = threadIdx.x;
    {
        float fn = (float)n;
        float mu = psum[t] / fn;
        float var = psumsq[t] / fn - mu * mu;
        float s = g[t] / sqrtf(var + 1e-5f);
        sc_s[t] = s; sh_s[t] = bt[t] - mu * s;
    }
    __syncthreads();

    int wave = t >> 6, lane = t & 63;
    int lm = lane & 15, q = lane >> 4;
    int r0 = blockIdx.x * 128;

    f32x4 acc[2][4];
#pragma unroll
    for (int i = 0; i < 2; ++i)
#pragma unroll
        for (int j = 0; j < 4; ++j) acc[i][j] = (f32x4){0.f, 0.f, 0.f, 0.f};

    int srow = t >> 3;   // 0..31
    int skc = t & 7;

    for (int kt = 0; kt < 4; ++kt) {
        int kc = kt * 64;
        float scr[8], shr[8];
        {
            int cb = kc + skc * 8;
            *(float4*)&scr[0] = *(const float4*)&sc_s[cb];
            *(float4*)&scr[4] = *(const float4*)&sc_s[cb + 4];
            *(float4*)&shr[0] = *(const float4*)&sh_s[cb];
            *(float4*)&shr[4] = *(const float4*)&sh_s[cb + 4];
        }
#pragma unroll
        for (int u = 0; u < 4; ++u) {
            int row = srow + u * 32;
            int ga = r0 + row; if (ga >= n) ga = n - 1;
            float4 av = *(const float4*)&A[(size_t)ga * KD + kc + skc * 8];
            unsigned short* us = (unsigned short*)&av;
#pragma unroll
            for (int k2 = 0; k2 < 8; ++k2)
                us[k2] = f2bf(fmaxf(bf2f(us[k2]) * scr[k2] + shr[k2], 0.f));
            *(float4*)&As[SWIZ(row, skc)] = av;
        }
#pragma unroll
        for (int u = 0; u < 2; ++u) {
            int c = t + u * 256;
            int row = c >> 3, kcc = c & 7;
            *(float4*)&Bs[SWIZ(row, kcc)] = *(const float4*)&W2[(size_t)row * HD + kc + kcc * 8];
        }
        __syncthreads();
#pragma unroll
        for (int kk = 0; kk < 2; ++kk) {
            bf16x8 af[2], bfv[4];
#pragma unroll
            for (int i = 0; i < 2; ++i)
                af[i] = *(bf16x8*)&As[SWIZ(wave * 32 + i * 16 + lm, kk * 4 + q)];
#pragma unroll
            for (int j = 0; j < 4; ++j)
                bfv[j] = *(bf16x8*)&Bs[SWIZ(j * 16 + lm, kk * 4 + q)];
#pragma unroll
            for (int i = 0; i < 2; ++i)
#pragma unroll
                for (int j = 0; j < 4; ++j)
                    acc[i][j] = __builtin_amdgcn_mfma_f32_16x16x32_bf16(af[i], bfv[j], acc[i][j], 0, 0, 0);
        }
        __syncthreads();
    }
#pragma unroll
    for (int i = 0; i < 2; ++i) {
        int rbase = r0 + wave * 32 + i * 16 + q * 4;
#pragma unroll
        for (int reg = 0; reg < 4; ++reg) {
            int r = rbase + reg;
            if (r >= n) continue;
#pragma unroll
            for (int j = 0; j < 4; ++j) {
                int c = j * 16 + lm;
                unsigned short v = f2bf(acc[i][j][reg]);
                if (c < 32) PL[(size_t)r * 32 + c] = v;
                else        PR[(size_t)r * 32 + (c - 32)] = v;
            }
        }
    }
}

// out = S@PL + PR + bias, routed. 4 nodes per wave (16 lanes x 2 cols each).
__global__ void head_agg(const unsigned short* __restrict__ PL, const unsigned short* __restrict__ PR,
                         const int* __restrict__ row_ptr, const int* __restrict__ col_idx,
                         const float* __restrict__ invdeg, const float* __restrict__ bcat,
                         float* __restrict__ out, int n) {
    int t = threadIdx.x;
    int sub = t >> 4;          // 0..15
    int l16 = t & 15;
    int node = blockIdx.x * 16 + sub;
    if (node >= n) return;
    int s = row_ptr[node], e = row_ptr[node + 1];
    int off = l16 * 2;
    float a0 = 0.f, a1 = 0.f;
    int i = s;
    for (; i + 4 <= e; i += 4) {
        int s0 = col_idx[i], s1 = col_idx[i + 1], s2 = col_idx[i + 2], s3 = col_idx[i + 3];
        unsigned v0 = *(const unsigned*)&PL[(size_t)s0 * 32 + off];
        unsigned v1 = *(const unsigned*)&PL[(size_t)s1 * 32 + off];
        unsigned v2 = *(const unsigned*)&PL[(size_t)s2 * 32 + off];
        unsigned v3 = *(const unsigned*)&PL[(size_t)s3 * 32 + off];
        a0 += bf2f((unsigned short)v0) + bf2f((unsigned short)v1) + bf2f((unsigned short)v2) + bf2f((unsigned short)v3);
        a1 += bf2f((unsigned short)(v0 >> 16)) + bf2f((unsigned short)(v1 >> 16))
            + bf2f((unsigned short)(v2 >> 16)) + bf2f((unsigned short)(v3 >> 16));
    }
    for (; i < e; ++i) {
        unsigned v = *(const unsigned*)&PL[(size_t)col_idx[i] * 32 + off];
        a0 += bf2f((unsigned short)v);
        a1 += bf2f((unsigned short)(v >> 16));
    }
    float inv = invdeg[node];
    unsigned vr = *(const unsigned*)&PR[(size_t)node * 32 + off];
    float o0 = a0 * inv + bf2f((unsigned short)vr) + bcat[off];
    float o1 = a1 * inv + bf2f((unsigned short)(vr >> 16)) + bcat[off + 1];
    int c0 = off, c1 = off + 1;
    if (c0 < 21)      out[(size_t)node * 21 + c0] = o0;
    else if (c0 < 23) out[(size_t)n * 21 + (size_t)node * 2 + (c0 - 21)] = o0;
    else if (c0 < 28) out[(size_t)n * 23 + (size_t)node * 5 + (c0 - 23)] = o0;
    if (c1 < 21)      out[(size_t)node * 21 + c1] = o1;
    else if (c1 < 23) out[(size_t)n * 21 + (size_t)node * 2 + (c1 - 21)] = o1;
    else if (c1 < 28) out[(size_t)n * 23 + (size_t)node * 5 + (c1 - 23)] = o1;
}

// ---------------- host ----------------
static inline char* align256(char* p) {
    return (char*)(((uintptr_t)p + 255) & ~(uintptr_t)255);
}

extern "C" void kernel_launch(void* const* d_in, const int* in_sizes, int n_in,
                              void* d_out, int out_size, void* d_ws, size_t ws_size,
                              hipStream_t stream) {
    const float* x    = (const float*)d_in[0];
    const int*   esrc = (const int*)d_in[1];
    const int*   edst = (const int*)d_in[2];
    const float* w1l = (const float*)d_in[3];  const float* w1r = (const float*)d_in[5];
    const float* g1  = (const float*)d_in[6];  const float* bt1 = (const float*)d_in[7];
    const float* w2l = (const float*)d_in[8];  const float* w2r = (const float*)d_in[10];
    const float* g2  = (const float*)d_in[11]; const float* bt2 = (const float*)d_in[12];
    const float* w3l = (const float*)d_in[13]; const float* w3r = (const float*)d_in[15];
    const float* g3  = (const float*)d_in[16]; const float* bt3 = (const float*)d_in[17];
    const float* wal = (const float*)d_in[18]; const float* ba = (const float*)d_in[19];
    const float* war = (const float*)d_in[20];
    const float* wsl = (const float*)d_in[21]; const float* bs = (const float*)d_in[22];
    const float* wsr = (const float*)d_in[23];
    const float* wel = (const float*)d_in[24]; const float* be = (const float*)d_in[25];
    const float* wer = (const float*)d_in[26];
    float* out = (float*)d_out;

    int N = in_sizes[0] / HD;
    int E = in_sizes[1];

    char* p = (char*)d_ws;
    size_t HB = (size_t)N * KD * sizeof(unsigned short);   // [N][512] bf16
    unsigned short* buf0 = (unsigned short*)p; p += HB;
    unsigned short* buf1 = (unsigned short*)p; p += HB;
    p = align256(p);
    unsigned short* PLb = (unsigned short*)p; p += (size_t)N * 32 * sizeof(unsigned short);
    unsigned short* PRb = (unsigned short*)p; p += (size_t)N * 32 * sizeof(unsigned short);
    p = align256(p);
    int* col_idx = (int*)p; p += sizeof(int) * (size_t)E;       p = align256(p);
    int* row_ptr = (int*)p; p += sizeof(int) * (size_t)(N + 1); p = align256(p);
    int* cnt     = (int*)p; p += sizeof(int) * (size_t)N;       // cnt+cursor contiguous (one memset)
    int* cursor  = (int*)p; p += sizeof(int) * (size_t)N;       p = align256(p);
    int* bsum    = (int*)p; p += sizeof(int) * 256;
    int* boff    = (int*)p; p += sizeof(int) * 256;             p = align256(p);
    float* invdeg   = (float*)p; p += sizeof(float) * (size_t)N; p = align256(p);
    float* zs[3]; float* zq[3];
    for (int l = 0; l < 3; ++l) {
        zs[l] = (float*)p; p += sizeof(float) * 256;
        zq[l] = (float*)p; p += sizeof(float) * 256;
    }
    p = align256(p);
    unsigned short* wc1 = (unsigned short*)p; p += sizeof(unsigned short) * HD * KD;
    unsigned short* wc2 = (unsigned short*)p; p += sizeof(unsigned short) * HD * KD;
    unsigned short* wc3 = (unsigned short*)p; p += sizeof(unsigned short) * HD * KD;
    unsigned short* w2h = (unsigned short*)p; p += sizeof(unsigned short) * 64 * HD;
    p = align256(p);
    float* bcat = (float*)p; p += sizeof(float) * 32;
    (void)ws_size; (void)n_in; (void)out_size;

    int nchunks = (N + 255) / 256;

    // CSR build + weight packing
    hipMemsetAsync(cnt, 0, sizeof(int) * 2 * (size_t)N, stream);
    hist_kernel<<<(E + 255) / 256, 256, 0, stream>>>(edst, cnt, E);
    chunk_reduce_kernel<<<nchunks, 256, 0, stream>>>(cnt, bsum, N);
    scan_chunks_kernel<<<1, 256, 0, stream>>>(bsum, boff, nchunks, &row_ptr[N], E);
    scan_final_kernel<<<nchunks, 256, 0, stream>>>(cnt, boff, row_ptr, invdeg, N);
    scatter_kernel<<<(E + 255) / 256, 256, 0, stream>>>(esrc, edst, row_ptr, cursor, col_idx, E);
    pack_layer_w<<<(HD * KD + 255) / 256, 256, 0, stream>>>(w1l, w1r, wc1);
    pack_layer_w<<<(HD * KD + 255) / 256, 256, 0, stream>>>(w2l, w2r, wc2);
    pack_layer_w<<<(HD * KD + 255) / 256, 256, 0, stream>>>(w3l, w3r, wc3);
    pack_heads2<<<(64 * HD + 255) / 256, 256, 0, stream>>>(wal, war, wsl, wsr, wel, wer,
                                                           ba, bs, be, w2h, bcat);
    convert_x_kernel<<<(N * 64 + 255) / 256, 256, 0, stream>>>(x, buf0, N);

    int aggGrid = (N + 3) / 4;
    int gemmGrid = (N + 127) / 128;

    unsigned short* cur = buf0;
    unsigned short* nxt = buf1;
    const unsigned short* wcs[3] = {wc1, wc2, wc3};
    const float* gs[3]  = {g1, g2, g3};
    const float* bts[3] = {bt1, bt2, bt3};

    for (int l = 0; l < 3; ++l) {
        const float* ps = (l > 0) ? zs[l - 1] : zs[0];
        const float* pq = (l > 0) ? zq[l - 1] : zq[0];
        const float* pg = (l > 0) ? gs[l - 1] : g1;
        const float* pb = (l > 0) ? bts[l - 1] : bt1;
        int apply = (l > 0) ? 1 : 0;
        // mean of BN'd(prev) features -> left half; also zeroes this layer's stat bufs
        agg_mean_fused<<<aggGrid, 256, 0, stream>>>(cur, row_ptr, col_idx, invdeg,
                                                    ps, pq, pg, pb, zs[l], zq[l], apply, N);
        // Z_l = [mean | BN(rawZ)] @ Wcat^T -> raw bf16 into nxt right half + stats_l
        // (layer bias omitted: exactly cancelled by batch-stat BN)
        gemm_mfma_stats<<<gemmGrid, 512, 0, stream>>>(cur, wcs[l], nxt,
                                                      ps, pq, pg, pb, zs[l], zq[l], apply, N);
        unsigned short* t2 = cur; cur = nxt; nxt = t2;
    }

    // heads: P = BN3(h3raw) @ [L|R]^T (K=256), then 28-wide aggregation (L2-resident gather)
    heads_pgemm<<<gemmGrid, 256, 0, stream>>>(cur + HD, w2h, zs[2], zq[2], g3, bt3, PLb, PRb, N);
    head_agg<<<(N + 15) / 16, 256, 0, stream>>>(PLb, PRb, row_ptr, col_idx, invdeg, bcat, out, N);
}